// Round 17
// baseline (45.073 us; speedup 1.0000x reference)
//
#include <hip/hip_runtime.h>
#include <math.h>

// SSIM loss. R17: STRIP=16 (512-wide x 16-row strip per 512-thread block).
// Insight: total waves was grid-capped at 4096 (16/CU, half of HW max) in
// every 32-row variant -> VALUBusy plateaued ~55%. Halving the strip gives
// 1024 blocks = 8192 waves = 32/CU (full), at +24% staging/hconv cost
// (vertical halo 26/16 vs 42/32). Everything else = R16's fully-static
// group instantiation:
//  - f16-packed LDS {p01,p23,g01,g23}, 1 ds_read_b128/tap, pk_fma hconv
//    with symmetric tap pairing (w[k]==w[10-k])
//  - 16-slot statically-indexed accumulator ring, fdot2 scatter, pruned
//    to valid output rows per group (compile-time)
//  - drain-free barrier (lgkmcnt(0) + s_barrier; vmcnt stays in flight)
// Spill ledger: one prefetch path, (512,2) budget, static indices only
// (R4/R5/R13 all spilled violating one of these). VGPR must stay <=64 for
// 8 waves/SIMD.

#define KW 11
#define HALF 5
#define STRIP 16
#define W 512
#define H 512
#define NT 512
#define SCOLS (W + 2*HALF)    // 522
#define NIN (STRIP + 2*HALF)  // 26 staged rows (26,27 of group 6 zeroed)

static constexpr float kC1 = 0.0001f;
static constexpr float kC2 = 0.0009f;

typedef decltype(__builtin_amdgcn_cvt_pkrtz(0.f, 0.f)) half2v;

__device__ __forceinline__ float sgpr_f(float v) {
    return __int_as_float(__builtin_amdgcn_readfirstlane(__float_as_int(v)));
}
__device__ __forceinline__ int bci(half2v h) { return __builtin_bit_cast(int, h); }
__device__ __forceinline__ half2v bch(int i) { return __builtin_bit_cast(half2v, i); }

// static scatter ranges: output row oo = 4G-10+idx must lie in [0, STRIP)
#define A_LO(G) ((10 - 4*(G)) > 0 ? (10 - 4*(G)) : 0)
#define A_HI(G) ((STRIP + 9 - 4*(G)) < 11 ? (STRIP + 9 - 4*(G)) : 11)
#define B_LO(G) ((10 - 4*(G)) > 2 ? (10 - 4*(G)) : 2)
#define B_HI(G) ((STRIP + 9 - 4*(G)) < 13 ? (STRIP + 9 - 4*(G)) : 13)

__global__ __launch_bounds__(NT, 2) void ssim_strip(
    const float* __restrict__ logits,
    const float* __restrict__ gts,
    const float* __restrict__ window,
    float* __restrict__ partial)
{
    __shared__ uint4 sq[2][SCOLS];   // {p01,p23,g01,g23} f16-pair bits
    __shared__ float red[NT / 64];

    const int x = threadIdx.x;

    // 1D taps = row sums of 2D window (sum(g)=1); SGPR-hoisted.
    float w[KW];
#pragma unroll
    for (int k = 0; k < KW; ++k) {
        float s = 0.f;
#pragma unroll
        for (int j = 0; j < KW; ++j) s += window[k * KW + j];
        w[k] = sgpr_f(s);
    }

    // f16 tap pairs (wk,wk) for pk hconv, SGPR ints.
    int wk2i[KW];
#pragma unroll
    for (int k = 0; k < KW; ++k)
        wk2i[k] = __builtin_amdgcn_readfirstlane(
            bci(__builtin_amdgcn_cvt_pkrtz(w[k], w[k])));

    // f16 weight pairs for the vertical scatter:
    //   rows (4G,4G+1):   idx d -> (w[10-d], w[11-d])    (wpAi)
    //   rows (4G+2,4G+3): idx p -> (w[12-p], w[13-p])    (wpBi, p-2 indexed)
    // FULL bounds guards (R12 lesson: w[-1] OOB).
    int wpAi[12], wpBi[12];
#pragma unroll
    for (int p = 0; p < 12; ++p) {
        const float a0 = (10 - p >= 0 && 10 - p <= 10) ? w[10 - p] : 0.f;
        const float a1 = (11 - p >= 0 && 11 - p <= 10) ? w[11 - p] : 0.f;
        wpAi[p] = __builtin_amdgcn_readfirstlane(
            bci(__builtin_amdgcn_cvt_pkrtz(a0, a1)));
        const int q = p + 2;
        const float b0 = (12 - q >= 0 && 12 - q <= 10) ? w[12 - q] : 0.f;
        const float b1 = (13 - q >= 0 && 13 - q <= 10) ? w[13 - q] : 0.f;
        wpBi[p] = __builtin_amdgcn_readfirstlane(
            bci(__builtin_amdgcn_cvt_pkrtz(b0, b1)));
    }

    const int img = blockIdx.x >> 5;          // 32 strips per image
    const int ty  = blockIdx.x & 31;
    const int y0  = ty * STRIP;
    const float* __restrict__ L = logits + (size_t)img * (H * W);
    const float* __restrict__ G = gts    + (size_t)img * (H * W);

    // zero halo columns once, both buffers
    if (x < 2 * HALF) {
        const int sc = (x < HALF) ? x : (W + x);
        sq[0][sc] = make_uint4(0, 0, 0, 0);
        sq[1][sc] = make_uint4(0, 0, 0, 0);
    }

    // 16-slot ring accumulators (all statically indexed; compiler folds
    // liveness -> ~60 VGPR total, measured R16)
    float P1[16], P2[16], PA[16], PB[16], PC[16];
#pragma unroll
    for (int i = 0; i < 16; ++i) {
        P1[i] = 0.f; P2[i] = 0.f; PA[i] = 0.f; PB[i] = 0.f; PC[i] = 0.f;
    }

    float pl[4], pgv[4];
#define PREFETCH_ROW(j, rr_expr)                                               \
    {                                                                          \
        const int row  = y0 - HALF + (rr_expr);                                \
        const int rowc = min(max(row, 0), H - 1);                              \
        const float mk = (row == rowc) ? 1.f : 0.f;                            \
        const float lv = L[rowc * W + x];                                      \
        const float gv = G[rowc * W + x];                                      \
        pl[j]  = mk * __builtin_amdgcn_rcpf(1.f + __expf(-lv));                \
        pgv[j] = mk * gv;                                                      \
    }
#pragma unroll
    for (int j = 0; j < 4; ++j) PREFETCH_ROW(j, j)

    float acc = 0.f;

#define SSIM_GROUP(GG)                                                         \
    {                                                                          \
        { /* stage rows 4G..4G+3 as f16 pairs */                               \
            uint4 q;                                                           \
            q.x = (unsigned)bci(__builtin_amdgcn_cvt_pkrtz(pl[0],  pl[1]));    \
            q.y = (unsigned)bci(__builtin_amdgcn_cvt_pkrtz(pl[2],  pl[3]));    \
            q.z = (unsigned)bci(__builtin_amdgcn_cvt_pkrtz(pgv[0], pgv[1]));   \
            q.w = (unsigned)bci(__builtin_amdgcn_cvt_pkrtz(pgv[2], pgv[3]));   \
            sq[(GG) & 1][x + HALF] = q;                                        \
        }                                                                      \
        if ((GG) < 5) {                                                        \
            _Pragma("unroll")                                                  \
            for (int j = 0; j < 4; ++j) PREFETCH_ROW(j, 4 * ((GG) + 1) + j)    \
        } else if ((GG) == 5) { /* group 6 = rows 24,25 + zeros */             \
            PREFETCH_ROW(0, 24)                                                \
            PREFETCH_ROW(1, 25)                                                \
            pl[2] = 0.f; pl[3] = 0.f; pgv[2] = 0.f; pgv[3] = 0.f;              \
        }                                                                      \
        asm volatile("s_waitcnt lgkmcnt(0)" ::: "memory");                     \
        __builtin_amdgcn_s_barrier();                                          \
        __builtin_amdgcn_sched_barrier(0);                                     \
        const half2v hz = bch(0);                                              \
        half2v h1a = hz, h1b = hz, h2a = hz, h2b = hz;                         \
        half2v hAa = hz, hAb = hz, hBa = hz, hBb = hz;                         \
        half2v hCa = hz, hCb = hz;                                             \
        _Pragma("unroll")                                                      \
        for (int k = 0; k < 5; ++k) { /* symmetric tap pairs (k, 10-k) */      \
            const uint4 qa = sq[(GG) & 1][x + k];                              \
            const uint4 qb = sq[(GG) & 1][x + 10 - k];                         \
            const half2v wk2 = bch(wk2i[k]);                                   \
            const half2v pa0 = bch((int)qa.x), pb0 = bch((int)qb.x);           \
            const half2v pa1 = bch((int)qa.y), pb1 = bch((int)qb.y);           \
            const half2v ga0 = bch((int)qa.z), gb0 = bch((int)qb.z);           \
            const half2v ga1 = bch((int)qa.w), gb1 = bch((int)qb.w);           \
            h1a += wk2 * (pa0 + pb0);  h1b += wk2 * (pa1 + pb1);               \
            h2a += wk2 * (ga0 + gb0);  h2b += wk2 * (ga1 + gb1);               \
            hAa += wk2 * (pa0 * pa0 + pb0 * pb0);                              \
            hAb += wk2 * (pa1 * pa1 + pb1 * pb1);                              \
            hBa += wk2 * (ga0 * ga0 + gb0 * gb0);                              \
            hBb += wk2 * (ga1 * ga1 + gb1 * gb1);                              \
            hCa += wk2 * (pa0 * ga0 + pb0 * gb0);                              \
            hCb += wk2 * (pa1 * ga1 + pb1 * gb1);                              \
        }                                                                      \
        { /* center tap k=5 */                                                 \
            const uint4 qc = sq[(GG) & 1][x + 5];                              \
            const half2v wk2 = bch(wk2i[5]);                                   \
            const half2v pc0 = bch((int)qc.x), pc1 = bch((int)qc.y);           \
            const half2v gc0 = bch((int)qc.z), gc1 = bch((int)qc.w);           \
            h1a += wk2 * pc0;  h1b += wk2 * pc1;                               \
            h2a += wk2 * gc0;  h2b += wk2 * gc1;                               \
            hAa += wk2 * (pc0 * pc0);  hAb += wk2 * (pc1 * pc1);               \
            hBa += wk2 * (gc0 * gc0);  hBb += wk2 * (gc1 * gc1);               \
            hCa += wk2 * (pc0 * gc0);  hCb += wk2 * (pc1 * gc1);               \
        }                                                                      \
        _Pragma("unroll")                                                      \
        for (int d = 0; d < 12; ++d) { /* rows (4G,4G+1), pruned static */     \
            if (d >= A_LO(GG) && d <= A_HI(GG)) {                              \
                const int s = (4 * (GG) + 6 + d) & 15;                         \
                const half2v wa = bch(wpAi[d]);                                \
                P1[s] = __builtin_amdgcn_fdot2(h1a, wa, P1[s], false);         \
                P2[s] = __builtin_amdgcn_fdot2(h2a, wa, P2[s], false);         \
                PA[s] = __builtin_amdgcn_fdot2(hAa, wa, PA[s], false);         \
                PB[s] = __builtin_amdgcn_fdot2(hBa, wa, PB[s], false);         \
                PC[s] = __builtin_amdgcn_fdot2(hCa, wa, PC[s], false);         \
            }                                                                  \
        }                                                                      \
        _Pragma("unroll")                                                      \
        for (int p = 2; p < 14; ++p) { /* rows (4G+2,4G+3); input row must */  \
            if (4 * (GG) + 2 < NIN &&     /* exist (G=6 rows 26,27 are pad) */ \
                p >= B_LO(GG) && p <= B_HI(GG)) {                              \
                const int s = (4 * (GG) + 6 + p) & 15;                         \
                const half2v wb2 = bch(wpBi[p - 2]);                           \
                P1[s] = __builtin_amdgcn_fdot2(h1b, wb2, P1[s], false);        \
                P2[s] = __builtin_amdgcn_fdot2(h2b, wb2, P2[s], false);        \
                PA[s] = __builtin_amdgcn_fdot2(hAb, wb2, PA[s], false);        \
                PB[s] = __builtin_amdgcn_fdot2(hBb, wb2, PB[s], false);        \
                PC[s] = __builtin_amdgcn_fdot2(hCb, wb2, PC[s], false);        \
            }                                                                  \
        }                                                                      \
        _Pragma("unroll")                                                      \
        for (int p = 0; p < 4; ++p) { /* emit rows 4G-10+p, static guard */    \
            const int oo = 4 * (GG) - 10 + p;                                  \
            if (oo >= 0 && oo < STRIP) {                                       \
                const int s = oo & 15;                                         \
                const float m1 = P1[s], m2 = P2[s];                            \
                const float mu11 = m1 * m1, mu22 = m2 * m2, mu12 = m1 * m2;    \
                const float s11 = PA[s] - mu11;                                \
                const float s22 = PB[s] - mu22;                                \
                const float s12 = PC[s] - mu12;                                \
                const float num = (2.f * mu12 + kC1) * (2.f * s12 + kC2);      \
                const float den = (mu11 + mu22 + kC1) * (s11 + s22 + kC2);     \
                acc += num * __builtin_amdgcn_rcpf(den);                       \
            }                                                                  \
        }                                                                      \
    }

    SSIM_GROUP(0)
    SSIM_GROUP(1)
    SSIM_GROUP(2)
    SSIM_GROUP(3)
    SSIM_GROUP(4)
    SSIM_GROUP(5)
    SSIM_GROUP(6)

#undef SSIM_GROUP
#undef PREFETCH_ROW

    // ---- block reduction ----
#pragma unroll
    for (int off = 32; off > 0; off >>= 1) acc += __shfl_xor(acc, off);
    if ((x & 63) == 0) red[x >> 6] = acc;
    __syncthreads();
    if (x == 0) {
        float s = 0.f;
#pragma unroll
        for (int i = 0; i < NT / 64; ++i) s += red[i];
        partial[blockIdx.x] = s;
    }
}

__global__ __launch_bounds__(256) void ssim_finalize(
    const float* __restrict__ partial, int nparts, double inv_count,
    float* __restrict__ out)
{
    __shared__ double sd[256];
    const int tid = threadIdx.x;
    double s = 0.0;
    for (int i = tid; i < nparts; i += 256) s += (double)partial[i];
    sd[tid] = s;
    __syncthreads();
    for (int st = 128; st > 0; st >>= 1) {
        if (tid < st) sd[tid] += sd[tid + st];
        __syncthreads();
    }
    if (tid == 0) out[0] = (float)(1.0 - sd[0] * inv_count);
}

extern "C" void kernel_launch(void* const* d_in, const int* in_sizes, int n_in,
                              void* d_out, int out_size, void* d_ws, size_t ws_size,
                              hipStream_t stream) {
    const float* logits = (const float*)d_in[0];
    const float* gts    = (const float*)d_in[1];
    const float* window = (const float*)d_in[2];
    float* out = (float*)d_out;

    const int nimg = in_sizes[0] / (H * W);   // 32
    const int nblocks = nimg * (H / STRIP);   // 1024

    float* partial = (float*)d_ws;

    ssim_strip<<<nblocks, NT, 0, stream>>>(logits, gts, window, partial);

    const double inv_count = 1.0 / ((double)nimg * H * W);
    ssim_finalize<<<1, 256, 0, stream>>>(partial, nblocks, inv_count, out);
}

// Round 18
// 44.477 us; speedup vs baseline: 1.0134x; 1.0134x over previous
//
#include <hip/hip_runtime.h>
#include <math.h>

// SSIM loss. 512-wide x 32-row strip per 512-thread block (R16 base, best
// at 39.3us). R18: 8-row SUPER-GROUPS -> 6 barriers instead of 11. Stage
// two f16-packed 4-row halves per barrier (LDS [2buf][2half][522]), then
// two compute phases back-to-back with mid-phase emit (pending window <=14
// rows -> same 16-slot static ring). Falsified levers ledger: barrier-drain
// (R15), more blocks (R8), wave-private staging (R14), finer strips (R17).
// Spill ledger: one prefetch path, (512,2) budget, static indices only.

#define KW 11
#define HALF 5
#define STRIP 32
#define W 512
#define H 512
#define NT 512
#define SCOLS (W + 2*HALF)    // 522

static constexpr float kC1 = 0.0001f;
static constexpr float kC2 = 0.0009f;

typedef decltype(__builtin_amdgcn_cvt_pkrtz(0.f, 0.f)) half2v;

__device__ __forceinline__ float sgpr_f(float v) {
    return __int_as_float(__builtin_amdgcn_readfirstlane(__float_as_int(v)));
}
__device__ __forceinline__ int bci(half2v h) { return __builtin_bit_cast(int, h); }
__device__ __forceinline__ half2v bch(int i) { return __builtin_bit_cast(half2v, i); }

// static scatter prune: output row oo = R0-10+idx must lie in [0, 31]
#define SA_LO(R0) ((10 - (R0)) > 0 ? (10 - (R0)) : 0)
#define SA_HI(R0) ((41 - (R0)) < 11 ? (41 - (R0)) : 11)
#define SB_LO(R0) ((10 - (R0)) > 2 ? (10 - (R0)) : 2)
#define SB_HI(R0) ((41 - (R0)) < 13 ? (41 - (R0)) : 13)

__global__ __launch_bounds__(NT, 2) void ssim_strip(
    const float* __restrict__ logits,
    const float* __restrict__ gts,
    const float* __restrict__ window,
    float* __restrict__ partial)
{
    __shared__ uint4 sq[2][2][SCOLS];   // [buf][half][col] {p01,p23,g01,g23}
    __shared__ float red[NT / 64];

    const int x = threadIdx.x;

    // 1D taps = row sums of 2D window (sum(g)=1); SGPR-hoisted.
    float w[KW];
#pragma unroll
    for (int k = 0; k < KW; ++k) {
        float s = 0.f;
#pragma unroll
        for (int j = 0; j < KW; ++j) s += window[k * KW + j];
        w[k] = sgpr_f(s);
    }

    // f16 tap pairs (wk,wk) for pk hconv, SGPR ints.
    int wk2i[KW];
#pragma unroll
    for (int k = 0; k < KW; ++k)
        wk2i[k] = __builtin_amdgcn_readfirstlane(
            bci(__builtin_amdgcn_cvt_pkrtz(w[k], w[k])));

    // f16 weight pairs for the vertical scatter:
    //   rows (R0,R0+1):   idx d -> (w[10-d], w[11-d])    (wpAi)
    //   rows (R0+2,R0+3): idx p -> (w[12-p], w[13-p])    (wpBi, p-2 indexed)
    // FULL bounds guards (R12 lesson: w[-1] OOB).
    int wpAi[12], wpBi[12];
#pragma unroll
    for (int p = 0; p < 12; ++p) {
        const float a0 = (10 - p >= 0 && 10 - p <= 10) ? w[10 - p] : 0.f;
        const float a1 = (11 - p >= 0 && 11 - p <= 10) ? w[11 - p] : 0.f;
        wpAi[p] = __builtin_amdgcn_readfirstlane(
            bci(__builtin_amdgcn_cvt_pkrtz(a0, a1)));
        const int q = p + 2;
        const float b0 = (12 - q >= 0 && 12 - q <= 10) ? w[12 - q] : 0.f;
        const float b1 = (13 - q >= 0 && 13 - q <= 10) ? w[13 - q] : 0.f;
        wpBi[p] = __builtin_amdgcn_readfirstlane(
            bci(__builtin_amdgcn_cvt_pkrtz(b0, b1)));
    }

    const int img = blockIdx.x >> 4;
    const int ty  = blockIdx.x & 15;
    const int y0  = ty * STRIP;
    const float* __restrict__ L = logits + (size_t)img * (H * W);
    const float* __restrict__ G = gts    + (size_t)img * (H * W);

    // zero halo columns once, both buffers/halves
    if (x < 2 * HALF) {
        const int sc = (x < HALF) ? x : (W + x);
        sq[0][0][sc] = make_uint4(0, 0, 0, 0);
        sq[0][1][sc] = make_uint4(0, 0, 0, 0);
        sq[1][0][sc] = make_uint4(0, 0, 0, 0);
        sq[1][1][sc] = make_uint4(0, 0, 0, 0);
    }

    // 16-slot ring accumulators (statically indexed; zero-after-emit keeps
    // the reuse invariant: slot oo&15 freed in the phase of row oo+10,
    // before row oo+16's first scatter)
    float P1[16], P2[16], PA[16], PB[16], PC[16];
#pragma unroll
    for (int i = 0; i < 16; ++i) {
        P1[i] = 0.f; P2[i] = 0.f; PA[i] = 0.f; PB[i] = 0.f; PC[i] = 0.f;
    }

    float pl8[8], pgv8[8];
#define PREFETCH_ROW(j, rr_expr)                                               \
    {                                                                          \
        const int row  = y0 - HALF + (rr_expr);                                \
        const int rowc = min(max(row, 0), H - 1);                              \
        const float mk = (row == rowc) ? 1.f : 0.f;                            \
        const float lv = L[rowc * W + x];                                      \
        const float gv = G[rowc * W + x];                                      \
        pl8[j]  = mk * __builtin_amdgcn_rcpf(1.f + __expf(-lv));               \
        pgv8[j] = mk * gv;                                                     \
    }
#pragma unroll
    for (int j = 0; j < 8; ++j) PREFETCH_ROW(j, j)

    float acc = 0.f;

#define STAGE_HALF(BB, HH, J0)                                                 \
    {                                                                          \
        uint4 q;                                                               \
        q.x = (unsigned)bci(__builtin_amdgcn_cvt_pkrtz(pl8[(J0)],     pl8[(J0) + 1])); \
        q.y = (unsigned)bci(__builtin_amdgcn_cvt_pkrtz(pl8[(J0) + 2], pl8[(J0) + 3])); \
        q.z = (unsigned)bci(__builtin_amdgcn_cvt_pkrtz(pgv8[(J0)],     pgv8[(J0) + 1])); \
        q.w = (unsigned)bci(__builtin_amdgcn_cvt_pkrtz(pgv8[(J0) + 2], pgv8[(J0) + 3])); \
        sq[BB][HH][x + HALF] = q;                                              \
    }

#define PHASE(BB, HH, R0)                                                      \
    {                                                                          \
        const half2v hz = bch(0);                                              \
        half2v h1a = hz, h1b = hz, h2a = hz, h2b = hz;                         \
        half2v hAa = hz, hAb = hz, hBa = hz, hBb = hz;                         \
        half2v hCa = hz, hCb = hz;                                             \
        _Pragma("unroll")                                                      \
        for (int k = 0; k < 5; ++k) { /* symmetric tap pairs (k, 10-k) */      \
            const uint4 qa = sq[BB][HH][x + k];                                \
            const uint4 qb = sq[BB][HH][x + 10 - k];                           \
            const half2v wk2 = bch(wk2i[k]);                                   \
            const half2v pa0 = bch((int)qa.x), pb0 = bch((int)qb.x);           \
            const half2v pa1 = bch((int)qa.y), pb1 = bch((int)qb.y);           \
            const half2v ga0 = bch((int)qa.z), gb0 = bch((int)qb.z);           \
            const half2v ga1 = bch((int)qa.w), gb1 = bch((int)qb.w);           \
            h1a += wk2 * (pa0 + pb0);  h1b += wk2 * (pa1 + pb1);               \
            h2a += wk2 * (ga0 + gb0);  h2b += wk2 * (ga1 + gb1);               \
            hAa += wk2 * (pa0 * pa0 + pb0 * pb0);                              \
            hAb += wk2 * (pa1 * pa1 + pb1 * pb1);                              \
            hBa += wk2 * (ga0 * ga0 + gb0 * gb0);                              \
            hBb += wk2 * (ga1 * ga1 + gb1 * gb1);                              \
            hCa += wk2 * (pa0 * ga0 + pb0 * gb0);                              \
            hCb += wk2 * (pa1 * ga1 + pb1 * gb1);                              \
        }                                                                      \
        { /* center tap k=5 */                                                 \
            const uint4 qc = sq[BB][HH][x + 5];                                \
            const half2v wk2 = bch(wk2i[5]);                                   \
            const half2v pc0 = bch((int)qc.x), pc1 = bch((int)qc.y);           \
            const half2v gc0 = bch((int)qc.z), gc1 = bch((int)qc.w);           \
            h1a += wk2 * pc0;  h1b += wk2 * pc1;                               \
            h2a += wk2 * gc0;  h2b += wk2 * gc1;                               \
            hAa += wk2 * (pc0 * pc0);  hAb += wk2 * (pc1 * pc1);               \
            hBa += wk2 * (gc0 * gc0);  hBb += wk2 * (gc1 * gc1);               \
            hCa += wk2 * (pc0 * gc0);  hCb += wk2 * (pc1 * gc1);               \
        }                                                                      \
        _Pragma("unroll")                                                      \
        for (int d = 0; d < 12; ++d) { /* rows (R0,R0+1), pruned static */     \
            if (d >= SA_LO(R0) && d <= SA_HI(R0)) {                            \
                const int s = ((R0) - 10 + d) & 15;                            \
                const half2v wa = bch(wpAi[d]);                                \
                P1[s] = __builtin_amdgcn_fdot2(h1a, wa, P1[s], false);         \
                P2[s] = __builtin_amdgcn_fdot2(h2a, wa, P2[s], false);         \
                PA[s] = __builtin_amdgcn_fdot2(hAa, wa, PA[s], false);         \
                PB[s] = __builtin_amdgcn_fdot2(hBa, wa, PB[s], false);         \
                PC[s] = __builtin_amdgcn_fdot2(hCa, wa, PC[s], false);         \
            }                                                                  \
        }                                                                      \
        _Pragma("unroll")                                                      \
        for (int p = 2; p < 14; ++p) { /* rows (R0+2,R0+3), pruned static */   \
            if (p >= SB_LO(R0) && p <= SB_HI(R0)) {                            \
                const int s = ((R0) - 10 + p) & 15;                            \
                const half2v wb2 = bch(wpBi[p - 2]);                           \
                P1[s] = __builtin_amdgcn_fdot2(h1b, wb2, P1[s], false);        \
                P2[s] = __builtin_amdgcn_fdot2(h2b, wb2, P2[s], false);        \
                PA[s] = __builtin_amdgcn_fdot2(hAb, wb2, PA[s], false);        \
                PB[s] = __builtin_amdgcn_fdot2(hBb, wb2, PB[s], false);        \
                PC[s] = __builtin_amdgcn_fdot2(hCb, wb2, PC[s], false);        \
            }                                                                  \
        }                                                                      \
        _Pragma("unroll")                                                      \
        for (int e = 0; e < 4; ++e) { /* emit rows R0-10+e, static guard */    \
            const int oo = (R0) - 10 + e;                                      \
            if (oo >= 0 && oo < STRIP) {                                       \
                const int s = oo & 15;                                         \
                const float m1 = P1[s], m2 = P2[s];                            \
                const float mu11 = m1 * m1, mu22 = m2 * m2, mu12 = m1 * m2;    \
                const float s11 = PA[s] - mu11;                                \
                const float s22 = PB[s] - mu22;                                \
                const float s12 = PC[s] - mu12;                                \
                const float num = (2.f * mu12 + kC1) * (2.f * s12 + kC2);      \
                const float den = (mu11 + mu22 + kC1) * (s11 + s22 + kC2);     \
                acc += num * __builtin_amdgcn_rcpf(den);                       \
                P1[s] = 0.f; P2[s] = 0.f;                                      \
                PA[s] = 0.f; PB[s] = 0.f; PC[s] = 0.f;                         \
            }                                                                  \
        }                                                                      \
    }

#define SUPER_FULL(SS)                                                         \
    {                                                                          \
        STAGE_HALF((SS) & 1, 0, 0)                                             \
        STAGE_HALF((SS) & 1, 1, 4)                                             \
        if ((SS) < 4) {                                                        \
            _Pragma("unroll")                                                  \
            for (int j = 0; j < 8; ++j) PREFETCH_ROW(j, 8 * ((SS) + 1) + j)    \
        } else {                                                               \
            PREFETCH_ROW(0, 40)                                                \
            PREFETCH_ROW(1, 41)                                                \
            _Pragma("unroll")                                                  \
            for (int j = 2; j < 8; ++j) { pl8[j] = 0.f; pgv8[j] = 0.f; }       \
        }                                                                      \
        asm volatile("s_waitcnt lgkmcnt(0)" ::: "memory");                     \
        __builtin_amdgcn_s_barrier();                                          \
        __builtin_amdgcn_sched_barrier(0);                                     \
        PHASE((SS) & 1, 0, 8 * (SS))                                           \
        PHASE((SS) & 1, 1, 8 * (SS) + 4)                                       \
    }

    SUPER_FULL(0)
    SUPER_FULL(1)
    SUPER_FULL(2)
    SUPER_FULL(3)
    SUPER_FULL(4)

    // ---- S=5: rows 40,41 (+2 zeros) in half 0 of buf 1; phase B's scatter
    // ranges are statically empty, so a single phase suffices ----
    STAGE_HALF(1, 0, 0)
    asm volatile("s_waitcnt lgkmcnt(0)" ::: "memory");
    __builtin_amdgcn_s_barrier();
    __builtin_amdgcn_sched_barrier(0);
    PHASE(1, 0, 40)

#undef SUPER_FULL
#undef PHASE
#undef STAGE_HALF
#undef PREFETCH_ROW

    // ---- block reduction ----
#pragma unroll
    for (int off = 32; off > 0; off >>= 1) acc += __shfl_xor(acc, off);
    if ((x & 63) == 0) red[x >> 6] = acc;
    __syncthreads();
    if (x == 0) {
        float s = 0.f;
#pragma unroll
        for (int i = 0; i < NT / 64; ++i) s += red[i];
        partial[blockIdx.x] = s;
    }
}

__global__ __launch_bounds__(256) void ssim_finalize(
    const float* __restrict__ partial, int nparts, double inv_count,
    float* __restrict__ out)
{
    __shared__ double sd[256];
    const int tid = threadIdx.x;
    double s = 0.0;
    for (int i = tid; i < nparts; i += 256) s += (double)partial[i];
    sd[tid] = s;
    __syncthreads();
    for (int st = 128; st > 0; st >>= 1) {
        if (tid < st) sd[tid] += sd[tid + st];
        __syncthreads();
    }
    if (tid == 0) out[0] = (float)(1.0 - sd[0] * inv_count);
}

extern "C" void kernel_launch(void* const* d_in, const int* in_sizes, int n_in,
                              void* d_out, int out_size, void* d_ws, size_t ws_size,
                              hipStream_t stream) {
    const float* logits = (const float*)d_in[0];
    const float* gts    = (const float*)d_in[1];
    const float* window = (const float*)d_in[2];
    float* out = (float*)d_out;

    const int nimg = in_sizes[0] / (H * W);   // 32
    const int nblocks = nimg * (H / STRIP);   // 512

    float* partial = (float*)d_ws;

    ssim_strip<<<nblocks, NT, 0, stream>>>(logits, gts, window, partial);

    const double inv_count = 1.0 / ((double)nimg * H * W);
    ssim_finalize<<<1, 256, 0, stream>>>(partial, nblocks, inv_count, out);
}

// Round 19
// 38.426 us; speedup vs baseline: 1.1730x; 1.1575x over previous
//
#include <hip/hip_runtime.h>
#include <math.h>

// SSIM loss. 512-wide x 32-row strip per 512-thread block (R16 base).
// R19: ALGEBRAIC FIELD MERGE 5 -> 4. SSIM's den needs only sigma1^2+sigma2^2
// = E[p^2]+E[g^2] - mu1^2 - mu2^2, so convolve s = p^2+g^2 as ONE field.
// Stage 4 fields {p, g, s, pg} as two f16-packed uint4 per column; products
// computed once at staging (squares were f16-rounded in the pk hconv anyway,
// so the rounding profile is unchanged):
//  - hconv: pure pk_fma accumulate, 88 ops/group (was 176)
//  - scatter: 4 fields x pruned slots, ~68 fdot2/group (was ~85)
//  - cost: +11 ds_read_b128, +12 staging muls per group. Net ~ -15% inst.
// Everything else = R16: fully-static group instantiation, 16-slot ring,
// drain-free barrier, one prefetch path, (512,2) budget.
// Falsified-lever ledger: barrier-drain (R15), more blocks (R8), wave-
// private (R14), finer strips (R17), super-groups (R18). Instruction count
// is the only lever that has never failed.

#define KW 11
#define HALF 5
#define STRIP 32
#define W 512
#define H 512
#define NT 512
#define SCOLS (W + 2*HALF)    // 522

static constexpr float kC1 = 0.0001f;
static constexpr float kC2 = 0.0009f;

typedef decltype(__builtin_amdgcn_cvt_pkrtz(0.f, 0.f)) half2v;

__device__ __forceinline__ float sgpr_f(float v) {
    return __int_as_float(__builtin_amdgcn_readfirstlane(__float_as_int(v)));
}
__device__ __forceinline__ int bci(half2v h) { return __builtin_bit_cast(int, h); }
__device__ __forceinline__ half2v bch(int i) { return __builtin_bit_cast(half2v, i); }

// static scatter ranges: output row oo = 4G-10+idx must lie in [0, 31]
#define A_LO(G) ((10 - 4*(G)) > 0 ? (10 - 4*(G)) : 0)
#define A_HI(G) ((41 - 4*(G)) < 11 ? (41 - 4*(G)) : 11)
#define B_LO(G) ((10 - 4*(G)) > 2 ? (10 - 4*(G)) : 2)
#define B_HI(G) ((41 - 4*(G)) < 13 ? (41 - 4*(G)) : 13)

__global__ __launch_bounds__(NT, 2) void ssim_strip(
    const float* __restrict__ logits,
    const float* __restrict__ gts,
    const float* __restrict__ window,
    float* __restrict__ partial)
{
    __shared__ uint4 sqA[2][SCOLS];  // {p01,p23,g01,g23}
    __shared__ uint4 sqB[2][SCOLS];  // {s01,s23,c01,c23}, s=p^2+g^2, c=p*g
    __shared__ float red[NT / 64];

    const int x = threadIdx.x;

    // 1D taps = row sums of 2D window (sum(g)=1); SGPR-hoisted.
    float w[KW];
#pragma unroll
    for (int k = 0; k < KW; ++k) {
        float s = 0.f;
#pragma unroll
        for (int j = 0; j < KW; ++j) s += window[k * KW + j];
        w[k] = sgpr_f(s);
    }

    // f16 tap pairs (wk,wk) for pk hconv, SGPR ints.
    int wk2i[KW];
#pragma unroll
    for (int k = 0; k < KW; ++k)
        wk2i[k] = __builtin_amdgcn_readfirstlane(
            bci(__builtin_amdgcn_cvt_pkrtz(w[k], w[k])));

    // f16 weight pairs for the vertical scatter:
    //   rows (4G,4G+1):   idx d -> (w[10-d], w[11-d])    (wpAi)
    //   rows (4G+2,4G+3): idx p -> (w[12-p], w[13-p])    (wpBi, p-2 indexed)
    // FULL bounds guards (R12 lesson: w[-1] OOB).
    int wpAi[12], wpBi[12];
#pragma unroll
    for (int p = 0; p < 12; ++p) {
        const float a0 = (10 - p >= 0 && 10 - p <= 10) ? w[10 - p] : 0.f;
        const float a1 = (11 - p >= 0 && 11 - p <= 10) ? w[11 - p] : 0.f;
        wpAi[p] = __builtin_amdgcn_readfirstlane(
            bci(__builtin_amdgcn_cvt_pkrtz(a0, a1)));
        const int q = p + 2;
        const float b0 = (12 - q >= 0 && 12 - q <= 10) ? w[12 - q] : 0.f;
        const float b1 = (13 - q >= 0 && 13 - q <= 10) ? w[13 - q] : 0.f;
        wpBi[p] = __builtin_amdgcn_readfirstlane(
            bci(__builtin_amdgcn_cvt_pkrtz(b0, b1)));
    }

    const int img = blockIdx.x >> 4;
    const int ty  = blockIdx.x & 15;
    const int y0  = ty * STRIP;
    const float* __restrict__ L = logits + (size_t)img * (H * W);
    const float* __restrict__ G = gts    + (size_t)img * (H * W);

    // zero halo columns once, both arrays/buffers
    if (x < 2 * HALF) {
        const int sc = (x < HALF) ? x : (W + x);
        sqA[0][sc] = make_uint4(0, 0, 0, 0);
        sqA[1][sc] = make_uint4(0, 0, 0, 0);
        sqB[0][sc] = make_uint4(0, 0, 0, 0);
        sqB[1][sc] = make_uint4(0, 0, 0, 0);
    }

    // 16-slot ring accumulators, 4 fields (statically indexed)
    float P1[16], P2[16], PS[16], PC[16];
#pragma unroll
    for (int i = 0; i < 16; ++i) {
        P1[i] = 0.f; P2[i] = 0.f; PS[i] = 0.f; PC[i] = 0.f;
    }

    float pl[4], pgv[4];
#define PREFETCH_ROW(j, rr_expr)                                               \
    {                                                                          \
        const int row  = y0 - HALF + (rr_expr);                                \
        const int rowc = min(max(row, 0), H - 1);                              \
        const float mk = (row == rowc) ? 1.f : 0.f;                            \
        const float lv = L[rowc * W + x];                                      \
        const float gv = G[rowc * W + x];                                      \
        pl[j]  = mk * __builtin_amdgcn_rcpf(1.f + __expf(-lv));                \
        pgv[j] = mk * gv;                                                      \
    }
#pragma unroll
    for (int j = 0; j < 4; ++j) PREFETCH_ROW(j, j)

    float acc = 0.f;

#define SSIM_GROUP(GG)                                                         \
    {                                                                          \
        { /* stage rows 4G..4G+3: {p,g} and {s,c} (s,c computed in f32) */     \
            const float s0 = pl[0]*pl[0] + pgv[0]*pgv[0];                      \
            const float s1 = pl[1]*pl[1] + pgv[1]*pgv[1];                      \
            const float s2 = pl[2]*pl[2] + pgv[2]*pgv[2];                      \
            const float s3 = pl[3]*pl[3] + pgv[3]*pgv[3];                      \
            const float c0 = pl[0]*pgv[0], c1 = pl[1]*pgv[1];                  \
            const float c2 = pl[2]*pgv[2], c3 = pl[3]*pgv[3];                  \
            uint4 qa, qb;                                                      \
            qa.x = (unsigned)bci(__builtin_amdgcn_cvt_pkrtz(pl[0],  pl[1]));   \
            qa.y = (unsigned)bci(__builtin_amdgcn_cvt_pkrtz(pl[2],  pl[3]));   \
            qa.z = (unsigned)bci(__builtin_amdgcn_cvt_pkrtz(pgv[0], pgv[1]));  \
            qa.w = (unsigned)bci(__builtin_amdgcn_cvt_pkrtz(pgv[2], pgv[3]));  \
            qb.x = (unsigned)bci(__builtin_amdgcn_cvt_pkrtz(s0, s1));          \
            qb.y = (unsigned)bci(__builtin_amdgcn_cvt_pkrtz(s2, s3));          \
            qb.z = (unsigned)bci(__builtin_amdgcn_cvt_pkrtz(c0, c1));          \
            qb.w = (unsigned)bci(__builtin_amdgcn_cvt_pkrtz(c2, c3));          \
            sqA[(GG) & 1][x + HALF] = qa;                                      \
            sqB[(GG) & 1][x + HALF] = qb;                                      \
        }                                                                      \
        if ((GG) < 9) {                                                        \
            _Pragma("unroll")                                                  \
            for (int j = 0; j < 4; ++j) PREFETCH_ROW(j, 4 * ((GG) + 1) + j)    \
        } else if ((GG) == 9) {                                                \
            PREFETCH_ROW(0, 40)                                                \
            PREFETCH_ROW(1, 41)                                                \
            pl[2] = 0.f; pl[3] = 0.f; pgv[2] = 0.f; pgv[3] = 0.f;              \
        }                                                                      \
        asm volatile("s_waitcnt lgkmcnt(0)" ::: "memory");                     \
        __builtin_amdgcn_s_barrier();                                          \
        __builtin_amdgcn_sched_barrier(0);                                     \
        const half2v hz = bch(0);                                              \
        half2v h1a = hz, h1b = hz, h2a = hz, h2b = hz;                         \
        half2v hSa = hz, hSb = hz, hCa = hz, hCb = hz;                         \
        _Pragma("unroll")                                                      \
        for (int k = 0; k < 5; ++k) { /* symmetric tap pairs (k, 10-k) */      \
            const uint4 qa = sqA[(GG) & 1][x + k];                             \
            const uint4 qb = sqA[(GG) & 1][x + 10 - k];                        \
            const uint4 ra = sqB[(GG) & 1][x + k];                             \
            const uint4 rb = sqB[(GG) & 1][x + 10 - k];                        \
            const half2v wk2 = bch(wk2i[k]);                                   \
            h1a += wk2 * (bch((int)qa.x) + bch((int)qb.x));                    \
            h1b += wk2 * (bch((int)qa.y) + bch((int)qb.y));                    \
            h2a += wk2 * (bch((int)qa.z) + bch((int)qb.z));                    \
            h2b += wk2 * (bch((int)qa.w) + bch((int)qb.w));                    \
            hSa += wk2 * (bch((int)ra.x) + bch((int)rb.x));                    \
            hSb += wk2 * (bch((int)ra.y) + bch((int)rb.y));                    \
            hCa += wk2 * (bch((int)ra.z) + bch((int)rb.z));                    \
            hCb += wk2 * (bch((int)ra.w) + bch((int)rb.w));                    \
        }                                                                      \
        { /* center tap k=5 */                                                 \
            const uint4 qc = sqA[(GG) & 1][x + 5];                             \
            const uint4 rc = sqB[(GG) & 1][x + 5];                             \
            const half2v wk2 = bch(wk2i[5]);                                   \
            h1a += wk2 * bch((int)qc.x);  h1b += wk2 * bch((int)qc.y);         \
            h2a += wk2 * bch((int)qc.z);  h2b += wk2 * bch((int)qc.w);         \
            hSa += wk2 * bch((int)rc.x);  hSb += wk2 * bch((int)rc.y);         \
            hCa += wk2 * bch((int)rc.z);  hCb += wk2 * bch((int)rc.w);         \
        }                                                                      \
        _Pragma("unroll")                                                      \
        for (int d = 0; d < 12; ++d) { /* rows (4G,4G+1), pruned static */     \
            if (d >= A_LO(GG) && d <= A_HI(GG)) {                              \
                const int s = (4 * (GG) + 6 + d) & 15;                         \
                const half2v wa = bch(wpAi[d]);                                \
                P1[s] = __builtin_amdgcn_fdot2(h1a, wa, P1[s], false);         \
                P2[s] = __builtin_amdgcn_fdot2(h2a, wa, P2[s], false);         \
                PS[s] = __builtin_amdgcn_fdot2(hSa, wa, PS[s], false);         \
                PC[s] = __builtin_amdgcn_fdot2(hCa, wa, PC[s], false);         \
            }                                                                  \
        }                                                                      \
        _Pragma("unroll")                                                      \
        for (int p = 2; p < 14; ++p) { /* rows (4G+2,4G+3), pruned static */   \
            if (p >= B_LO(GG) && p <= B_HI(GG)) {                              \
                const int s = (4 * (GG) + 6 + p) & 15;                         \
                const half2v wb2 = bch(wpBi[p - 2]);                           \
                P1[s] = __builtin_amdgcn_fdot2(h1b, wb2, P1[s], false);        \
                P2[s] = __builtin_amdgcn_fdot2(h2b, wb2, P2[s], false);        \
                PS[s] = __builtin_amdgcn_fdot2(hSb, wb2, PS[s], false);        \
                PC[s] = __builtin_amdgcn_fdot2(hCb, wb2, PC[s], false);        \
            }                                                                  \
        }                                                                      \
        _Pragma("unroll")                                                      \
        for (int p = 0; p < 4; ++p) { /* emit rows 4G-10+p, static guard */    \
            const int oo = 4 * (GG) - 10 + p;                                  \
            if (oo >= 0 && oo < STRIP) {                                       \
                const int s = oo & 15;                                         \
                const float m1 = P1[s], m2 = P2[s];                            \
                const float mu11 = m1 * m1, mu22 = m2 * m2, mu12 = m1 * m2;    \
                const float s12 = PC[s] - mu12;                                \
                const float sAB = PS[s] - mu11 - mu22;                         \
                const float num = (2.f * mu12 + kC1) * (2.f * s12 + kC2);      \
                const float den = (mu11 + mu22 + kC1) * (sAB + kC2);           \
                acc += num * __builtin_amdgcn_rcpf(den);                       \
                P1[s] = 0.f; P2[s] = 0.f; PS[s] = 0.f; PC[s] = 0.f;            \
            }                                                                  \
        }                                                                      \
    }

    SSIM_GROUP(0)
    SSIM_GROUP(1)
    SSIM_GROUP(2)
    SSIM_GROUP(3)
    SSIM_GROUP(4)
    SSIM_GROUP(5)
    SSIM_GROUP(6)
    SSIM_GROUP(7)
    SSIM_GROUP(8)
    SSIM_GROUP(9)
    SSIM_GROUP(10)

#undef SSIM_GROUP
#undef PREFETCH_ROW

    // ---- block reduction ----
#pragma unroll
    for (int off = 32; off > 0; off >>= 1) acc += __shfl_xor(acc, off);
    if ((x & 63) == 0) red[x >> 6] = acc;
    __syncthreads();
    if (x == 0) {
        float s = 0.f;
#pragma unroll
        for (int i = 0; i < NT / 64; ++i) s += red[i];
        partial[blockIdx.x] = s;
    }
}

__global__ __launch_bounds__(256) void ssim_finalize(
    const float* __restrict__ partial, int nparts, double inv_count,
    float* __restrict__ out)
{
    __shared__ double sd[256];
    const int tid = threadIdx.x;
    double s = 0.0;
    for (int i = tid; i < nparts; i += 256) s += (double)partial[i];
    sd[tid] = s;
    __syncthreads();
    for (int st = 128; st > 0; st >>= 1) {
        if (tid < st) sd[tid] += sd[tid + st];
        __syncthreads();
    }
    if (tid == 0) out[0] = (float)(1.0 - sd[0] * inv_count);
}

extern "C" void kernel_launch(void* const* d_in, const int* in_sizes, int n_in,
                              void* d_out, int out_size, void* d_ws, size_t ws_size,
                              hipStream_t stream) {
    const float* logits = (const float*)d_in[0];
    const float* gts    = (const float*)d_in[1];
    const float* window = (const float*)d_in[2];
    float* out = (float*)d_out;

    const int nimg = in_sizes[0] / (H * W);   // 32
    const int nblocks = nimg * (H / STRIP);   // 512

    float* partial = (float*)d_ws;

    ssim_strip<<<nblocks, NT, 0, stream>>>(logits, gts, window, partial);

    const double inv_count = 1.0 / ((double)nimg * H * W);
    ssim_finalize<<<1, 256, 0, stream>>>(partial, nblocks, inv_count, out);
}

// Round 20
// 36.246 us; speedup vs baseline: 1.2435x; 1.0602x over previous
//
#include <hip/hip_runtime.h>
#include <math.h>

// SSIM loss. R20: COLUMN-PAIRING. 512x32 strip per 256-thread block; thread
// t owns output cols 2t,2t+1. Their 11-tap windows overlap in 12 staged
// cols -> 24 b128 reads per 2 outputs (12/col vs 22/col in R19): per-CU LDS
// traffic halves (R19 accounting: dur ~ VALU-time + LDS-pipe-time, 17+21us;
// LDS was co-dominant). Staged arrays split by column parity (16B stride
// kept); each entry read once feeds both outputs with static weights.
//  - 4 fields {p,g,s=p^2+g^2,c=p*g} f16-packed (R19 algebraic merge)
//  - fully-static group instantiation, 16-slot ring x 2 cols, fdot2 scatter
//    pruned per group (R16), drain-free barrier (lgkmcnt(0)+s_barrier)
//  - float2 global loads (cols adjacent), one prefetch path
// Falsified levers: barrier-drain(R15), more blocks(R8), wave-private(R14),
// finer strips(R17), super-groups(R18). Working lever: instruction/traffic
// count. Spill ledger: static indices, one prefetch path, generous budget.

#define KW 11
#define HALF 5
#define STRIP 32
#define W 512
#define H 512
#define NT 256
#define NE 264               // e/o array length (halo idx 0..2, 259..261)

static constexpr float kC1 = 0.0001f;
static constexpr float kC2 = 0.0009f;

typedef decltype(__builtin_amdgcn_cvt_pkrtz(0.f, 0.f)) half2v;

__device__ __forceinline__ float sgpr_f(float v) {
    return __int_as_float(__builtin_amdgcn_readfirstlane(__float_as_int(v)));
}
__device__ __forceinline__ int bci(half2v h) { return __builtin_bit_cast(int, h); }
__device__ __forceinline__ half2v bch(int i) { return __builtin_bit_cast(half2v, i); }

// static scatter ranges: output row oo = 4G-10+idx must lie in [0, 31]
#define A_LO(G) ((10 - 4*(G)) > 0 ? (10 - 4*(G)) : 0)
#define A_HI(G) ((41 - 4*(G)) < 11 ? (41 - 4*(G)) : 11)
#define B_LO(G) ((10 - 4*(G)) > 2 ? (10 - 4*(G)) : 2)
#define B_HI(G) ((41 - 4*(G)) < 13 ? (41 - 4*(G)) : 13)

__global__ __launch_bounds__(NT, 2) void ssim_strip(
    const float* __restrict__ logits,
    const float* __restrict__ gts,
    const float* __restrict__ window,
    float* __restrict__ partial)
{
    // [buf][idx]; even cols in eA/eB, odd in oA/oB. col 2m -> e[m+3],
    // col 2m+1 -> o[m+3]. A = {p01,p23,g01,g23}, B = {s01,s23,c01,c23}.
    __shared__ uint4 eA[2][NE], oA[2][NE], eB[2][NE], oB[2][NE];
    __shared__ float red[NT / 64];

    const int t = threadIdx.x;

    // 1D taps = row sums of 2D window (sum(g)=1); SGPR-hoisted.
    float w[KW];
#pragma unroll
    for (int k = 0; k < KW; ++k) {
        float s = 0.f;
#pragma unroll
        for (int j = 0; j < KW; ++j) s += window[k * KW + j];
        w[k] = sgpr_f(s);
    }

    // f16 tap pairs (wk,wk), SGPR ints.
    int wk2i[KW];
#pragma unroll
    for (int k = 0; k < KW; ++k)
        wk2i[k] = __builtin_amdgcn_readfirstlane(
            bci(__builtin_amdgcn_cvt_pkrtz(w[k], w[k])));

    // f16 weight pairs for the vertical scatter (FULL guards - R12 lesson):
    //   rows (4G,4G+1):   idx d -> (w[10-d], w[11-d])    (wpAi)
    //   rows (4G+2,4G+3): idx p -> (w[12-p], w[13-p])    (wpBi, p-2 indexed)
    int wpAi[12], wpBi[12];
#pragma unroll
    for (int p = 0; p < 12; ++p) {
        const float a0 = (10 - p >= 0 && 10 - p <= 10) ? w[10 - p] : 0.f;
        const float a1 = (11 - p >= 0 && 11 - p <= 10) ? w[11 - p] : 0.f;
        wpAi[p] = __builtin_amdgcn_readfirstlane(
            bci(__builtin_amdgcn_cvt_pkrtz(a0, a1)));
        const int q = p + 2;
        const float b0 = (12 - q >= 0 && 12 - q <= 10) ? w[12 - q] : 0.f;
        const float b1 = (13 - q >= 0 && 13 - q <= 10) ? w[13 - q] : 0.f;
        wpBi[p] = __builtin_amdgcn_readfirstlane(
            bci(__builtin_amdgcn_cvt_pkrtz(b0, b1)));
    }

    const int img = blockIdx.x >> 4;
    const int ty  = blockIdx.x & 15;
    const int y0  = ty * STRIP;
    const float* __restrict__ L = logits + (size_t)img * (H * W);
    const float* __restrict__ G = gts    + (size_t)img * (H * W);

    // zero halo entries once (indices 0..2 and 259..261), both buffers
    if (t < 6) {
        const int zi = (t < 3) ? t : (256 + t);   // 0,1,2,259,260,261
        const uint4 z = make_uint4(0, 0, 0, 0);
        eA[0][zi] = z; eA[1][zi] = z; oA[0][zi] = z; oA[1][zi] = z;
        eB[0][zi] = z; eB[1][zi] = z; oB[0][zi] = z; oB[1][zi] = z;
    }

    // 16-slot rings, 4 fields x 2 output columns (statically indexed)
    float Pe1[16], Pe2[16], PeS[16], PeC[16];
    float Po1[16], Po2[16], PoS[16], PoC[16];
#pragma unroll
    for (int i = 0; i < 16; ++i) {
        Pe1[i] = 0.f; Pe2[i] = 0.f; PeS[i] = 0.f; PeC[i] = 0.f;
        Po1[i] = 0.f; Po2[i] = 0.f; PoS[i] = 0.f; PoC[i] = 0.f;
    }

    // prefetch: 4 rows x 2 cols (float2, cols adjacent)
    float ple[4], pge[4], plo[4], pgo[4];
#define PREFETCH_ROW(j, rr_expr)                                               \
    {                                                                          \
        const int row  = y0 - HALF + (rr_expr);                                \
        const int rowc = min(max(row, 0), H - 1);                              \
        const float mk = (row == rowc) ? 1.f : 0.f;                            \
        const float2 lv = *(const float2*)(L + (size_t)rowc * W + 2 * t);      \
        const float2 gv = *(const float2*)(G + (size_t)rowc * W + 2 * t);      \
        ple[j] = mk * __builtin_amdgcn_rcpf(1.f + __expf(-lv.x));              \
        plo[j] = mk * __builtin_amdgcn_rcpf(1.f + __expf(-lv.y));              \
        pge[j] = mk * gv.x;                                                    \
        pgo[j] = mk * gv.y;                                                    \
    }
#pragma unroll
    for (int j = 0; j < 4; ++j) PREFETCH_ROW(j, j)

    float acc = 0.f;

#define STAGE_PARITY(BB, PLX, PGX, EARR_A, EARR_B)                             \
    {                                                                          \
        const float s0 = PLX[0]*PLX[0] + PGX[0]*PGX[0];                        \
        const float s1 = PLX[1]*PLX[1] + PGX[1]*PGX[1];                        \
        const float s2 = PLX[2]*PLX[2] + PGX[2]*PGX[2];                        \
        const float s3 = PLX[3]*PLX[3] + PGX[3]*PGX[3];                        \
        const float c0 = PLX[0]*PGX[0], c1 = PLX[1]*PGX[1];                    \
        const float c2 = PLX[2]*PGX[2], c3 = PLX[3]*PGX[3];                    \
        uint4 qa, qb;                                                          \
        qa.x = (unsigned)bci(__builtin_amdgcn_cvt_pkrtz(PLX[0], PLX[1]));      \
        qa.y = (unsigned)bci(__builtin_amdgcn_cvt_pkrtz(PLX[2], PLX[3]));      \
        qa.z = (unsigned)bci(__builtin_amdgcn_cvt_pkrtz(PGX[0], PGX[1]));      \
        qa.w = (unsigned)bci(__builtin_amdgcn_cvt_pkrtz(PGX[2], PGX[3]));      \
        qb.x = (unsigned)bci(__builtin_amdgcn_cvt_pkrtz(s0, s1));              \
        qb.y = (unsigned)bci(__builtin_amdgcn_cvt_pkrtz(s2, s3));              \
        qb.z = (unsigned)bci(__builtin_amdgcn_cvt_pkrtz(c0, c1));              \
        qb.w = (unsigned)bci(__builtin_amdgcn_cvt_pkrtz(c2, c3));              \
        EARR_A[BB][t + 3] = qa;                                                \
        EARR_B[BB][t + 3] = qb;                                                \
    }

#define FMA8(H1A,H1B,H2A,H2B,HSA,HSB,HCA,HCB, QA, QB, WW)                      \
        H1A += (WW) * bch((int)(QA).x);  H1B += (WW) * bch((int)(QA).y);       \
        H2A += (WW) * bch((int)(QA).z);  H2B += (WW) * bch((int)(QA).w);       \
        HSA += (WW) * bch((int)(QB).x);  HSB += (WW) * bch((int)(QB).y);       \
        HCA += (WW) * bch((int)(QB).z);  HCB += (WW) * bch((int)(QB).w);

#define SSIM_GROUP(GG)                                                         \
    {                                                                          \
        STAGE_PARITY((GG) & 1, ple, pge, eA, eB)                               \
        STAGE_PARITY((GG) & 1, plo, pgo, oA, oB)                               \
        if ((GG) < 9) {                                                        \
            _Pragma("unroll")                                                  \
            for (int j = 0; j < 4; ++j) PREFETCH_ROW(j, 4 * ((GG) + 1) + j)    \
        } else if ((GG) == 9) {                                                \
            PREFETCH_ROW(0, 40)                                                \
            PREFETCH_ROW(1, 41)                                                \
            ple[2] = 0.f; ple[3] = 0.f; pge[2] = 0.f; pge[3] = 0.f;            \
            plo[2] = 0.f; plo[3] = 0.f; pgo[2] = 0.f; pgo[3] = 0.f;            \
        }                                                                      \
        asm volatile("s_waitcnt lgkmcnt(0)" ::: "memory");                     \
        __builtin_amdgcn_s_barrier();                                          \
        __builtin_amdgcn_sched_barrier(0);                                     \
        const half2v hz = bch(0);                                              \
        half2v e1a = hz, e1b = hz, e2a = hz, e2b = hz;                         \
        half2v eSa = hz, eSb = hz, eCa = hz, eCb = hz;                         \
        half2v o1a = hz, o1b = hz, o2a = hz, o2b = hz;                         \
        half2v oSa = hz, oSb = hz, oCa = hz, oCb = hz;                         \
        _Pragma("unroll")                                                      \
        for (int i = 0; i < 6; ++i) { /* odd-parity entries o[t+i] */          \
            const uint4 qo = oA[(GG) & 1][t + i];                              \
            const uint4 ro = oB[(GG) & 1][t + i];                              \
            const half2v we = bch(wk2i[2 * i]);   /* even out, d=2i */         \
            FMA8(e1a,e1b,e2a,e2b,eSa,eSb,eCa,eCb, qo, ro, we)                  \
            if (i >= 1) {                         /* odd out, d=2i-1 */        \
                const half2v wo = bch(wk2i[2 * i - 1]);                        \
                FMA8(o1a,o1b,o2a,o2b,oSa,oSb,oCa,oCb, qo, ro, wo)              \
            }                                                                  \
        }                                                                      \
        _Pragma("unroll")                                                      \
        for (int i = 0; i < 6; ++i) { /* even-parity entries e[t+1+i] */       \
            const uint4 qe = eA[(GG) & 1][t + 1 + i];                          \
            const uint4 re = eB[(GG) & 1][t + 1 + i];                          \
            const half2v wo = bch(wk2i[2 * i]);   /* odd out, d=2i */          \
            FMA8(o1a,o1b,o2a,o2b,oSa,oSb,oCa,oCb, qe, re, wo)                  \
            if (i <= 4) {                         /* even out, d=2i+1 */       \
                const half2v we2 = bch(wk2i[2 * i + 1]);                       \
                FMA8(e1a,e1b,e2a,e2b,eSa,eSb,eCa,eCb, qe, re, we2)             \
            }                                                                  \
        }                                                                      \
        _Pragma("unroll")                                                      \
        for (int d = 0; d < 12; ++d) { /* rows (4G,4G+1), pruned static */     \
            if (d >= A_LO(GG) && d <= A_HI(GG)) {                              \
                const int s = (4 * (GG) + 6 + d) & 15;                         \
                const half2v wa = bch(wpAi[d]);                                \
                Pe1[s] = __builtin_amdgcn_fdot2(e1a, wa, Pe1[s], false);       \
                Pe2[s] = __builtin_amdgcn_fdot2(e2a, wa, Pe2[s], false);       \
                PeS[s] = __builtin_amdgcn_fdot2(eSa, wa, PeS[s], false);       \
                PeC[s] = __builtin_amdgcn_fdot2(eCa, wa, PeC[s], false);       \
                Po1[s] = __builtin_amdgcn_fdot2(o1a, wa, Po1[s], false);       \
                Po2[s] = __builtin_amdgcn_fdot2(o2a, wa, Po2[s], false);       \
                PoS[s] = __builtin_amdgcn_fdot2(oSa, wa, PoS[s], false);       \
                PoC[s] = __builtin_amdgcn_fdot2(oCa, wa, PoC[s], false);       \
            }                                                                  \
        }                                                                      \
        _Pragma("unroll")                                                      \
        for (int p = 2; p < 14; ++p) { /* rows (4G+2,4G+3), pruned static */   \
            if (p >= B_LO(GG) && p <= B_HI(GG)) {                              \
                const int s = (4 * (GG) + 6 + p) & 15;                         \
                const half2v wb2 = bch(wpBi[p - 2]);                           \
                Pe1[s] = __builtin_amdgcn_fdot2(e1b, wb2, Pe1[s], false);      \
                Pe2[s] = __builtin_amdgcn_fdot2(e2b, wb2, Pe2[s], false);      \
                PeS[s] = __builtin_amdgcn_fdot2(eSb, wb2, PeS[s], false);      \
                PeC[s] = __builtin_amdgcn_fdot2(eCb, wb2, PeC[s], false);      \
                Po1[s] = __builtin_amdgcn_fdot2(o1b, wb2, Po1[s], false);      \
                Po2[s] = __builtin_amdgcn_fdot2(o2b, wb2, Po2[s], false);      \
                PoS[s] = __builtin_amdgcn_fdot2(oSb, wb2, PoS[s], false);      \
                PoC[s] = __builtin_amdgcn_fdot2(oCb, wb2, PoC[s], false);      \
            }                                                                  \
        }                                                                      \
        _Pragma("unroll")                                                      \
        for (int p = 0; p < 4; ++p) { /* emit rows 4G-10+p, static guard */    \
            const int oo = 4 * (GG) - 10 + p;                                  \
            if (oo >= 0 && oo < STRIP) {                                       \
                const int s = oo & 15;                                         \
                {                                                              \
                    const float m1 = Pe1[s], m2 = Pe2[s];                      \
                    const float mu11 = m1*m1, mu22 = m2*m2, mu12 = m1*m2;      \
                    const float s12 = PeC[s] - mu12;                           \
                    const float sAB = PeS[s] - mu11 - mu22;                    \
                    const float num = (2.f*mu12 + kC1) * (2.f*s12 + kC2);      \
                    const float den = (mu11 + mu22 + kC1) * (sAB + kC2);       \
                    acc += num * __builtin_amdgcn_rcpf(den);                   \
                    Pe1[s] = 0.f; Pe2[s] = 0.f; PeS[s] = 0.f; PeC[s] = 0.f;    \
                }                                                              \
                {                                                              \
                    const float m1 = Po1[s], m2 = Po2[s];                      \
                    const float mu11 = m1*m1, mu22 = m2*m2, mu12 = m1*m2;      \
                    const float s12 = PoC[s] - mu12;                           \
                    const float sAB = PoS[s] - mu11 - mu22;                    \
                    const float num = (2.f*mu12 + kC1) * (2.f*s12 + kC2);      \
                    const float den = (mu11 + mu22 + kC1) * (sAB + kC2);       \
                    acc += num * __builtin_amdgcn_rcpf(den);                   \
                    Po1[s] = 0.f; Po2[s] = 0.f; PoS[s] = 0.f; PoC[s] = 0.f;    \
                }                                                              \
            }                                                                  \
        }                                                                      \
    }

    SSIM_GROUP(0)
    SSIM_GROUP(1)
    SSIM_GROUP(2)
    SSIM_GROUP(3)
    SSIM_GROUP(4)
    SSIM_GROUP(5)
    SSIM_GROUP(6)
    SSIM_GROUP(7)
    SSIM_GROUP(8)
    SSIM_GROUP(9)
    SSIM_GROUP(10)

#undef SSIM_GROUP
#undef FMA8
#undef STAGE_PARITY
#undef PREFETCH_ROW

    // ---- block reduction ----
#pragma unroll
    for (int off = 32; off > 0; off >>= 1) acc += __shfl_xor(acc, off);
    if ((t & 63) == 0) red[t >> 6] = acc;
    __syncthreads();
    if (t == 0) {
        float s = 0.f;
#pragma unroll
        for (int i = 0; i < NT / 64; ++i) s += red[i];
        partial[blockIdx.x] = s;
    }
}

__global__ __launch_bounds__(256) void ssim_finalize(
    const float* __restrict__ partial, int nparts, double inv_count,
    float* __restrict__ out)
{
    __shared__ double sd[256];
    const int tid = threadIdx.x;
    double s = 0.0;
    for (int i = tid; i < nparts; i += 256) s += (double)partial[i];
    sd[tid] = s;
    __syncthreads();
    for (int st = 128; st > 0; st >>= 1) {
        if (tid < st) sd[tid] += sd[tid + st];
        __syncthreads();
    }
    if (tid == 0) out[0] = (float)(1.0 - sd[0] * inv_count);
}

extern "C" void kernel_launch(void* const* d_in, const int* in_sizes, int n_in,
                              void* d_out, int out_size, void* d_ws, size_t ws_size,
                              hipStream_t stream) {
    const float* logits = (const float*)d_in[0];
    const float* gts    = (const float*)d_in[1];
    const float* window = (const float*)d_in[2];
    float* out = (float*)d_out;

    const int nimg = in_sizes[0] / (H * W);   // 32
    const int nblocks = nimg * (H / STRIP);   // 512

    float* partial = (float*)d_ws;

    ssim_strip<<<nblocks, NT, 0, stream>>>(logits, gts, window, partial);

    const double inv_count = 1.0 / ((double)nimg * H * W);
    ssim_finalize<<<1, 256, 0, stream>>>(partial, nblocks, inv_count, out);
}